// Round 7
// baseline (158.830 us; speedup 1.0000x reference)
//
#include <hip/hip_runtime.h>

#define NN 4096
#define FIN 128
#define NHEAD 4
#define NHID 16
#define NCOL 64
#define SLOPE 0.2f
#define CHUNK 64
#define NCH 64      // NN / CHUNK
#define NCOLS 17    // 16 value cols + denominator col
#define NBLK 512

__device__ __forceinline__ float lrelu(float v){ return v > 0.f ? v : SLOPE * v; }

// Device-scope arrive-and-spin barrier. Counter zeroed by K1 each launch.
// Release: threadfence (L2 writeback) before arrive; acquire: threadfence (L2 inv)
// after the count completes. All NBLK blocks are co-resident by construction.
__device__ __forceinline__ void gbar(int* cnt, int nblk){
  __syncthreads();
  if (threadIdx.x == 0){
    __threadfence();
    __hip_atomic_fetch_add(cnt, 1, __ATOMIC_RELEASE, __HIP_MEMORY_SCOPE_AGENT);
    while (__hip_atomic_load(cnt, __ATOMIC_ACQUIRE, __HIP_MEMORY_SCOPE_AGENT) < nblk)
      __builtin_amdgcn_s_sleep(16);
    __threadfence();
  }
  __syncthreads();
}

// K1: h = x@W (+ src/dst epilogue). 512 blocks x 8 rows. Also zeroes barrier slots.
__global__ __launch_bounds__(256) void gemm_h_k(const float* __restrict__ x,
                                                const float* __restrict__ W,
                                                const float* __restrict__ aw,
                                                float* __restrict__ h,
                                                float* __restrict__ src,
                                                float* __restrict__ dst,
                                                int* __restrict__ bar){
  __shared__ float wl[FIN][NCOL];    // 32 KB
  __shared__ float xl[8][FIN];       // 4 KB
  __shared__ float hs[8][NCOL + 1];  // 2 KB
  int t = threadIdx.x;
  if (blockIdx.x == 0 && t < 2) bar[t * 64] = 0;   // plain store; kernel-boundary flush
  int row0 = blockIdx.x * 8;
  for (int k = t; k < FIN * NCOL; k += 256) wl[k >> 6][k & 63] = W[k];
  for (int k = t; k < 8 * FIN; k += 256) xl[k >> 7][k & 127] = x[row0 * FIN + k];
  __syncthreads();
  int col = t & 63, rb = t >> 6;     // rb wave-uniform -> xl reads broadcast
  float a0 = 0.f, a1 = 0.f;
  #pragma unroll
  for (int d = 0; d < FIN; ++d){
    float wv = wl[d][col];           // 2-way bank alias across 64 lanes: free
    a0 = fmaf(xl[rb * 2][d],     wv, a0);
    a1 = fmaf(xl[rb * 2 + 1][d], wv, a1);
  }
  h[(row0 + rb * 2) * NCOL + col] = a0;     hs[rb * 2][col] = a0;
  h[(row0 + rb * 2 + 1) * NCOL + col] = a1; hs[rb * 2 + 1][col] = a1;
  __syncthreads();
  if (t < 32){
    int r = t >> 2, hd = t & 3;
    float s = 0.f, d = 0.f;
    #pragma unroll
    for (int f = 0; f < NHID; ++f){
      float v = hs[r][hd * NHID + f];
      s = fmaf(v, aw[f], s);
      d = fmaf(v, aw[NHID + f], d);
    }
    src[hd * NN + row0 + r] = s;
    dst[hd * NN + row0 + r] = d;
  }
}

// K2: three phases with two in-kernel device barriers.
union S2 {
  struct { unsigned long long keys[8 * 513]; } r;                         // 32.8 KB
  struct { float e02[CHUNK], e1[CHUNK];
           float hl[CHUNK][NCOLS], PLs[CHUNK][NCOLS], SLs[CHUNK][NCOLS]; } a; // 13.6 KB
  struct { float oP[NCH + 1][68]; float oS[NCH][68]; float ds[NN]; } o;   // 50.3 KB
};

__global__ __launch_bounds__(256, 2) void fused2_k(
    const float* __restrict__ h, const float* __restrict__ src,
    const float* __restrict__ dst,
    float* __restrict__ dsort, int* __restrict__ perm,
    float* __restrict__ PL, float* __restrict__ SL,
    float* __restrict__ ctP, float* __restrict__ ctS,
    int* __restrict__ bar, float* __restrict__ out)
{
  __shared__ S2 sm;
  const int b = blockIdx.x;
  const int t = threadIdx.x;

  // ---------- Phase 0: rank-by-counting + scatter (b -> 128 i-blk x 4 heads) ----
  {
    int ib = b & 127, hd = b >> 7;
    const float* dp = dst + hd * NN;
    for (int j = t; j < NN; j += 256){
      unsigned int bb = __float_as_uint(dp[j]);
      bb ^= (bb & 0x80000000u) ? 0xFFFFFFFFu : 0x80000000u;  // float -> sortable uint
      sm.r.keys[(j >> 9) * 513 + (j & 511)] =
          ((unsigned long long)bb << 32) | (unsigned int)j;
    }
    __syncthreads();
    int il = t >> 3, jseg = t & 7;
    int i = ib * 32 + il;
    unsigned long long my = sm.r.keys[(i >> 9) * 513 + (i & 511)];
    const unsigned long long* kp = &sm.r.keys[jseg * 513];
    int cnt = 0;
    #pragma unroll 8
    for (int kk = 0; kk < 512; ++kk) cnt += (kp[kk] < my) ? 1 : 0;
    cnt += __shfl_down(cnt, 4);
    cnt += __shfl_down(cnt, 2);
    cnt += __shfl_down(cnt, 1);
    if (jseg == 0){
      dsort[hd * NN + cnt] = dp[i];
      perm[hd * NN + cnt]  = i;
    }
  }
  gbar(&bar[0], NBLK);

  // ---------- Phase 1: per-(head,chunk) local scans (blocks < 256 only) ---------
  if (b < 256){
    int ch = b & 63, hd = b >> 6;
    int base = ch * CHUNK;
    const float* ds = dsort + hd * NN;
    const int*   pm = perm + hd * NN;
    if (t < CHUNK){
      float d = ds[base + t];
      sm.a.e02[t] = __expf(0.2f * d);
      sm.a.e1[t]  = __expf(d);
      sm.a.hl[t][16] = 1.0f;
    }
    {
      int col = t & 15, r0 = t >> 4;
      #pragma unroll
      for (int it = 0; it < 4; ++it){
        int r = it * 16 + r0;
        sm.a.hl[r][col] = h[pm[base + r] * NCOL + hd * NHID + col];
      }
    }
    __syncthreads();
    if (t < NCOLS){
      int col = t;
      float run = 0.f;
      #pragma unroll
      for (int r = 0; r < CHUNK; ++r){
        sm.a.PLs[r][col] = run;
        run = fmaf(sm.a.e02[r], sm.a.hl[r][col], run);
      }
      ctP[ch * 68 + hd * 17 + col] = run;
    } else if (t >= 64 && t < 64 + NCOLS){
      int col = t - 64;
      float rs = 0.f;
      #pragma unroll
      for (int r = CHUNK - 1; r >= 0; --r){
        rs = fmaf(sm.a.e1[r], sm.a.hl[r][col], rs);
        sm.a.SLs[r][col] = rs;
      }
      ctS[ch * 68 + hd * 17 + col] = rs;
    }
    __syncthreads();
    for (int idx = t; idx < NCOLS * CHUNK; idx += 256){
      int col = idx >> 6, r = idx & 63;
      PL[(hd * 17 + col) * NN + base + r] = sm.a.PLs[r][col];
      SL[(hd * 17 + col) * NN + base + r] = sm.a.SLs[r][col];
    }
  }
  gbar(&bar[64], NBLK);

  // ---------- Phase 2: ct-scan (LDS) + LDS binary search + combine --------------
  {
    int hd = b & 3, ig = b >> 2;             // block: 32 i's of one head
    for (int j = t; j < NN; j += 256) sm.o.ds[j] = dsort[hd * NN + j];
    for (int idx = t; idx < NCH * 68; idx += 256){
      (&sm.o.oP[0][0])[idx] = ctP[idx];
      (&sm.o.oS[0][0])[idx] = ctS[idx];
    }
    __syncthreads();
    if (t < 68){
      float run = 0.f;
      #pragma unroll
      for (int c = 0; c < NCH; ++c){ float v = sm.o.oP[c][t]; sm.o.oP[c][t] = run; run += v; }
      sm.o.oP[NCH][t] = run;                 // grand totals
    } else if (t >= 128 && t < 196){
      int cc = t - 128;
      float rs = 0.f;
      #pragma unroll
      for (int c = NCH - 1; c >= 0; --c){ float v = sm.o.oS[c][cc]; sm.o.oS[c][cc] = rs; rs += v; }
    }
    __syncthreads();
    int tg = t >> 3, q = t & 7;              // 8 threads per (i) pair, head fixed
    int i = ig * 32 + tg;
    float s = src[hd * NN + i];
    float tthr = -s;
    int lo = 0, hi = NN;
    while (lo < hi){
      int mid = (lo + hi) >> 1;
      if (sm.o.ds[mid] < tthr) lo = mid + 1; else hi = mid;
    }
    int k = lo;                              // ranks < k take the 0.2 branch
    float* op = out + i * NCOL + hd * NHID;
    if (k == NN){                            // all in 0.2 branch: alpha cancels
      float inv = 1.0f / sm.o.oP[NCH][hd * 17 + 16];
      int f0 = q * 2;
      op[f0]     = sm.o.oP[NCH][hd * 17 + f0] * inv;
      op[f0 + 1] = sm.o.oP[NCH][hd * 17 + f0 + 1] * inv;
    } else {
      float m = lrelu(s + sm.o.ds[NN - 1]);
      float alpha = __expf(0.2f * s - m);
      float beta  = __expf(s - m);
      int ch = k >> 6;
      const float* PLp = PL + (hd * 17) * NN + k;
      const float* SLp = SL + (hd * 17) * NN + k;
      float den = alpha * (PLp[16 * NN] + sm.o.oP[ch][hd * 17 + 16])
                + beta  * (SLp[16 * NN] + sm.o.oS[ch][hd * 17 + 16]);
      float inv = 1.0f / den;
      #pragma unroll
      for (int ff = 0; ff < 2; ++ff){
        int f = q * 2 + ff;
        float num = alpha * (PLp[f * NN] + sm.o.oP[ch][hd * 17 + f])
                  + beta  * (SLp[f * NN] + sm.o.oS[ch][hd * 17 + f]);
        op[f] = num * inv;
      }
    }
  }
}

extern "C" void kernel_launch(void* const* d_in, const int* in_sizes, int n_in,
                              void* d_out, int out_size, void* d_ws, size_t ws_size,
                              hipStream_t stream){
  const float* x  = (const float*)d_in[0];
  // d_in[1] = adj : UNUSED by the reference (no masking) — never read it.
  const float* W  = (const float*)d_in[2];
  const float* aw = (const float*)d_in[3];
  float* out = (float*)d_out;
  float* ws  = (float*)d_ws;

  float* h     = ws;                  // 262144
  float* src   = ws + 262144;         // 16384
  float* dst   = ws + 278528;         // 16384
  float* dsort = ws + 294912;         // 16384
  int*   perm  = (int*)(ws + 311296); // 16384
  float* PL    = ws + 327680;         // 278528
  float* SL    = ws + 606208;         // 278528
  float* ctP   = ws + 884736;         // 4352
  float* ctS   = ws + 889088;         // 4352
  int*   bar   = (int*)(ws + 893440); // 128 ints (2 padded slots)
  // total ~3.58 MB

  gemm_h_k<<<NBLK, 256, 0, stream>>>(x, W, aw, h, src, dst, bar);
  fused2_k<<<NBLK, 256, 0, stream>>>(h, src, dst, dsort, perm, PL, SL, ctP, ctS, bar, out);
}

// Round 8
// 33.542 us; speedup vs baseline: 4.7352x; 4.7352x over previous
//
#include <hip/hip_runtime.h>

#define NN 4096
#define FIN 128
#define NHEAD 4
#define NHID 16
#define NCOL 64
#define SLOPE 0.2f
#define CHUNK 64
#define NCH 64      // NN / CHUNK
#define NCOLS 17    // 16 value cols + denominator col
#define RPAD 20     // padded row stride for PL2/SL2 (17 -> 20, float4-friendly)

__device__ __forceinline__ float lrelu(float v){ return v > 0.f ? v : SLOPE * v; }

// float bits -> order-preserving unsigned
__device__ __forceinline__ unsigned fkey(float f){
  unsigned b = __float_as_uint(f);
  return b ^ ((b & 0x80000000u) ? 0xFFFFFFFFu : 0x80000000u);
}
__device__ __forceinline__ float fkey_inv(unsigned k){
  unsigned b = (k & 0x80000000u) ? (k ^ 0x80000000u) : ~k;
  return __uint_as_float(b);
}

// K1: h = x@W (4096x128 @ 128x64) + fused src/dst epilogue. 512 blocks x 8 rows.
__global__ __launch_bounds__(256) void gemm_h_k(const float* __restrict__ x,
                                                const float* __restrict__ W,
                                                const float* __restrict__ aw,
                                                float* __restrict__ h,
                                                float* __restrict__ src,
                                                float* __restrict__ dst){
  __shared__ __align__(16) float wl[FIN][NCOL];  // 32 KB, same layout as W
  __shared__ float xlT[FIN][10];                 // transposed x tile, pad 10
  __shared__ float hs[8][NCOL + 1];
  int t = threadIdx.x;
  int row0 = blockIdx.x * 8;
  for (int k4 = t; k4 < FIN * NCOL / 4; k4 += 256)
    ((float4*)&wl[0][0])[k4] = ((const float4*)W)[k4];
  for (int k = t; k < 8 * FIN; k += 256){
    int r = k >> 7, d = k & 127;
    xlT[d][r] = x[(row0 + r) * FIN + d];         // coalesced global, stride-10 LDS
  }
  __syncthreads();
  int col = t & 63, rb = t >> 6;                 // rb wave-uniform
  float a0 = 0.f, a1 = 0.f;
  #pragma unroll
  for (int d = 0; d < FIN; ++d){
    float wv = wl[d][col];                       // 2-way alias: free
    float2 xv = *(const float2*)&xlT[d][rb * 2]; // wave-uniform b64 broadcast
    a0 = fmaf(xv.x, wv, a0);
    a1 = fmaf(xv.y, wv, a1);
  }
  h[(row0 + rb * 2) * NCOL + col] = a0;     hs[rb * 2][col] = a0;
  h[(row0 + rb * 2 + 1) * NCOL + col] = a1; hs[rb * 2 + 1][col] = a1;
  __syncthreads();
  if (t < 32){
    int r = t >> 2, hd = t & 3;
    float s = 0.f, d = 0.f;
    #pragma unroll
    for (int f = 0; f < NHID; ++f){
      float v = hs[r][hd * NHID + f];
      s = fmaf(v, aw[f], s);
      d = fmaf(v, aw[NHID + f], d);
    }
    src[hd * NN + row0 + r] = s;
    dst[hd * NN + row0 + r] = d;
  }
}

// K2: rank-by-counting + scatter of packed (key,idx) u64. 128x4 blocks.
__global__ __launch_bounds__(256) void ranksc_k(const float* __restrict__ dst,
                                                unsigned long long* __restrict__ ksort,
                                                unsigned* __restrict__ dkey){
  int ib = blockIdx.x;   // 0..127 -> 32 i's each
  int hd = blockIdx.y;   // 0..3
  __shared__ __align__(16) unsigned long long keys[8 * 514];  // 16B-aligned segs
  int t = threadIdx.x;
  const float* dp = dst + hd * NN;
  for (int j = t; j < NN; j += 256)
    keys[(j >> 9) * 514 + (j & 511)] =
        ((unsigned long long)fkey(dp[j]) << 32) | (unsigned)j;
  __syncthreads();
  int il = t >> 3, jseg = t & 7;
  int i = ib * 32 + il;
  unsigned long long my = keys[(i >> 9) * 514 + (i & 511)];
  const ulonglong2* kp2 = (const ulonglong2*)&keys[jseg * 514];
  int cnt = 0;
  #pragma unroll 8
  for (int q = 0; q < 256; ++q){               // 2 keys per ds_read_b128
    ulonglong2 kk = kp2[q];
    cnt += (kk.x < my) ? 1 : 0;
    cnt += (kk.y < my) ? 1 : 0;
  }
  cnt += __shfl_down(cnt, 4);
  cnt += __shfl_down(cnt, 2);
  cnt += __shfl_down(cnt, 1);
  if (jseg == 0){
    ksort[hd * NN + cnt] = my;                 // unique rank (idx breaks ties)
    dkey[hd * NN + cnt]  = (unsigned)(my >> 32);
  }
}

// K3: per-(head,chunk) local prefix/suffix scans -> transposed padded PL2/SL2.
__global__ __launch_bounds__(256) void scanA_k(const float* __restrict__ h,
                                               const unsigned long long* __restrict__ ksort,
                                               float* __restrict__ PL2,
                                               float* __restrict__ SL2,
                                               float* __restrict__ ctP,
                                               float* __restrict__ ctS){
  int ch = blockIdx.x;   // 64
  int hd = blockIdx.y;   // 4
  int t = threadIdx.x;
  int base = ch * CHUNK;
  __shared__ float e02[CHUNK], e1[CHUNK];
  __shared__ int   pms[CHUNK];
  __shared__ float hl[CHUNK][RPAD];
  __shared__ float PLs[CHUNK][RPAD], SLs[CHUNK][RPAD];
  if (t < CHUNK){
    unsigned long long key = ksort[hd * NN + base + t];
    float d = fkey_inv((unsigned)(key >> 32));
    e02[t] = __expf(0.2f * d);
    e1[t]  = __expf(d);
    pms[t] = (int)(unsigned)key;
    hl[t][16] = 1.0f;
  }
  __syncthreads();
  {
    int col = t & 15, r0 = t >> 4;
    #pragma unroll
    for (int it = 0; it < 4; ++it){
      int r = it * 16 + r0;
      hl[r][col] = h[pms[r] * NCOL + hd * NHID + col];
    }
  }
  __syncthreads();
  if (t < NCOLS){
    int col = t;
    float run = 0.f;
    #pragma unroll
    for (int r = 0; r < CHUNK; ++r){
      PLs[r][col] = run;                        // exclusive
      run = fmaf(e02[r], hl[r][col], run);
    }
    ctP[ch * 68 + hd * 17 + col] = run;
  } else if (t >= 64 && t < 64 + NCOLS){
    int col = t - 64;
    float rs = 0.f;
    #pragma unroll
    for (int r = CHUNK - 1; r >= 0; --r){
      rs = fmaf(e1[r], hl[r][col], rs);
      SLs[r][col] = rs;                         // inclusive
    }
    ctS[ch * 68 + hd * 17 + col] = rs;
  }
  __syncthreads();
  // contiguous coalesced writes (pad cols carry garbage, never read)
  #pragma unroll
  for (int n = 0; n < 5; ++n){
    int idx = n * 256 + t;                      // 5*256 = 64*20
    int r = idx / RPAD, c = idx % RPAD;
    PL2[(hd * NN + base + r) * RPAD + c] = PLs[r][c];
    SL2[(hd * NN + base + r) * RPAD + c] = SLs[r][c];
  }
}

// K4: LDS ct-scan + LDS binary search + float4 combine. 256 blocks x 64 pairs.
__global__ __launch_bounds__(256) void out_k(const float* __restrict__ src,
                                             const unsigned* __restrict__ dkey,
                                             const float* __restrict__ PL2,
                                             const float* __restrict__ SL2,
                                             const float* __restrict__ ctP,
                                             const float* __restrict__ ctS,
                                             float* __restrict__ out){
  __shared__ __align__(16) unsigned dk[NN];        // 16 KB sorted keys
  __shared__ __align__(16) float oP[NCH + 1][68];  // 17.7 KB (row NCH = totals)
  __shared__ __align__(16) float oS[NCH][68];      // 17.4 KB
  int t = threadIdx.x;
  int hd = blockIdx.x & 3, ig = blockIdx.x >> 2;
  const unsigned* dkp = dkey + hd * NN;
  #pragma unroll
  for (int n = 0; n < 4; ++n)
    ((uint4*)dk)[n * 256 + t] = ((const uint4*)dkp)[n * 256 + t];
  #pragma unroll
  for (int n = 0; n < 5; ++n){
    int idx = n * 256 + t;
    if (idx < 1088){
      ((float4*)&oP[0][0])[idx] = ((const float4*)ctP)[idx];
      ((float4*)&oS[0][0])[idx] = ((const float4*)ctS)[idx];
    }
  }
  __syncthreads();
  if (t < 68){
    float run = 0.f;
    #pragma unroll
    for (int c = 0; c < NCH; ++c){ float v = oP[c][t]; oP[c][t] = run; run += v; }
    oP[NCH][t] = run;
  } else if (t >= 128 && t < 196){
    int cc = t - 128;
    float rs = 0.f;
    #pragma unroll
    for (int c = NCH - 1; c >= 0; --c){ float v = oS[c][cc]; oS[c][cc] = rs; rs += v; }
  }
  __syncthreads();
  int p = t >> 2, q = t & 3;            // 64 pairs x 4 threads
  int i = ig * 64 + p;
  float s = src[hd * NN + i];
  unsigned tu = fkey(-s);
  int lo = 0, hi = NN;
  while (lo < hi){                      // 12 LDS-latency hops
    int mid = (lo + hi) >> 1;
    if (dk[mid] < tu) lo = mid + 1; else hi = mid;
  }
  int k = lo;                           // ranks < k take the 0.2 branch
  float4 res;
  if (k == NN){                         // all in 0.2 branch: alpha cancels
    float inv = 1.0f / oP[NCH][hd * 17 + 16];
    res.x = oP[NCH][hd * 17 + q * 4 + 0] * inv;
    res.y = oP[NCH][hd * 17 + q * 4 + 1] * inv;
    res.z = oP[NCH][hd * 17 + q * 4 + 2] * inv;
    res.w = oP[NCH][hd * 17 + q * 4 + 3] * inv;
  } else {
    float dmax = fkey_inv(dk[NN - 1]);
    float m = lrelu(s + dmax);
    float alpha = __expf(0.2f * s - m);
    float beta  = __expf(s - m);
    int ch = k >> 6;
    const float* P2 = PL2 + (size_t)(hd * NN + k) * RPAD;
    const float* S2 = SL2 + (size_t)(hd * NN + k) * RPAD;
    float4 p4 = *(const float4*)(P2 + q * 4);
    float4 s4 = *(const float4*)(S2 + q * 4);
    float den = alpha * (P2[16] + oP[ch][hd * 17 + 16])
              + beta  * (S2[16] + oS[ch][hd * 17 + 16]);
    float inv = 1.0f / den;
    res.x = (alpha * (p4.x + oP[ch][hd * 17 + q * 4 + 0])
           + beta  * (s4.x + oS[ch][hd * 17 + q * 4 + 0])) * inv;
    res.y = (alpha * (p4.y + oP[ch][hd * 17 + q * 4 + 1])
           + beta  * (s4.y + oS[ch][hd * 17 + q * 4 + 1])) * inv;
    res.z = (alpha * (p4.z + oP[ch][hd * 17 + q * 4 + 2])
           + beta  * (s4.z + oS[ch][hd * 17 + q * 4 + 2])) * inv;
    res.w = (alpha * (p4.w + oP[ch][hd * 17 + q * 4 + 3])
           + beta  * (s4.w + oS[ch][hd * 17 + q * 4 + 3])) * inv;
  }
  *(float4*)(out + i * NCOL + hd * NHID + q * 4) = res;
}

extern "C" void kernel_launch(void* const* d_in, const int* in_sizes, int n_in,
                              void* d_out, int out_size, void* d_ws, size_t ws_size,
                              hipStream_t stream){
  const float* x  = (const float*)d_in[0];
  // d_in[1] = adj : UNUSED by the reference (no masking) — never read it.
  const float* W  = (const float*)d_in[2];
  const float* aw = (const float*)d_in[3];
  float* out = (float*)d_out;
  float* ws  = (float*)d_ws;

  float*              h     = ws;                                   // 262144
  float*              src   = ws + 262144;                          // 16384
  float*              dst   = ws + 278528;                          // 16384
  unsigned long long* ksort = (unsigned long long*)(ws + 294912);   // 16384 u64 (16B-aligned)
  unsigned*           dkey  = (unsigned*)(ws + 327680);             // 16384
  float*              PL2   = ws + 344064;                          // 4*4096*20 = 327680
  float*              SL2   = ws + 671744;                          // 327680
  float*              ctP   = ws + 999424;                          // 4352
  float*              ctS   = ws + 1003776;                         // 4352
  // total ~4.03 MB

  gemm_h_k<<<512, 256, 0, stream>>>(x, W, aw, h, src, dst);
  ranksc_k<<<dim3(128, NHEAD), 256, 0, stream>>>(dst, ksort, dkey);
  scanA_k<<<dim3(NCH, NHEAD), 256, 0, stream>>>(h, ksort, PL2, SL2, ctP, ctS);
  out_k<<<256, 256, 0, stream>>>(src, dkey, PL2, SL2, ctP, ctS, out);
}

// Round 9
// 28.551 us; speedup vs baseline: 5.5630x; 1.1748x over previous
//
#include <hip/hip_runtime.h>

#define NN 4096
#define FIN 128
#define NHEAD 4
#define NHID 16
#define NCOL 64
#define SLOPE 0.2f
#define CHUNK 64
#define NCH 64      // NN / CHUNK
#define NCOLS 17    // 16 value cols + denominator col
#define RPAD 20     // padded row stride for PL2/SL2 (17 -> 20, float4-friendly)

__device__ __forceinline__ float lrelu(float v){ return v > 0.f ? v : SLOPE * v; }

// float bits -> order-preserving unsigned
__device__ __forceinline__ unsigned fkey(float f){
  unsigned b = __float_as_uint(f);
  return b ^ ((b & 0x80000000u) ? 0xFFFFFFFFu : 0x80000000u);
}
__device__ __forceinline__ float fkey_inv(unsigned k){
  unsigned b = (k & 0x80000000u) ? (k ^ 0x80000000u) : ~k;
  return __uint_as_float(b);
}

// K1: h = x@W (4096x128 @ 128x64) + fused src/dst epilogue. 512 blocks x 8 rows.
__global__ __launch_bounds__(256) void gemm_h_k(const float* __restrict__ x,
                                                const float* __restrict__ W,
                                                const float* __restrict__ aw,
                                                float* __restrict__ h,
                                                float* __restrict__ src,
                                                float* __restrict__ dst){
  __shared__ __align__(16) float wl[FIN][NCOL];  // 32 KB, same layout as W
  __shared__ float xlT[FIN][10];                 // transposed x tile, pad 10
  __shared__ float hs[8][NCOL + 1];
  int t = threadIdx.x;
  int row0 = blockIdx.x * 8;
  for (int k4 = t; k4 < FIN * NCOL / 4; k4 += 256)
    ((float4*)&wl[0][0])[k4] = ((const float4*)W)[k4];
  for (int k = t; k < 8 * FIN; k += 256){
    int r = k >> 7, d = k & 127;
    xlT[d][r] = x[(row0 + r) * FIN + d];         // coalesced global, stride-10 LDS
  }
  __syncthreads();
  int col = t & 63, rb = t >> 6;                 // rb wave-uniform
  float a0 = 0.f, a1 = 0.f;
  #pragma unroll
  for (int d = 0; d < FIN; ++d){
    float wv = wl[d][col];                       // 2-way alias: free
    float2 xv = *(const float2*)&xlT[d][rb * 2]; // wave-uniform b64 broadcast
    a0 = fmaf(xv.x, wv, a0);
    a1 = fmaf(xv.y, wv, a1);
  }
  h[(row0 + rb * 2) * NCOL + col] = a0;     hs[rb * 2][col] = a0;
  h[(row0 + rb * 2 + 1) * NCOL + col] = a1; hs[rb * 2 + 1][col] = a1;
  __syncthreads();
  if (t < 32){
    int r = t >> 2, hd = t & 3;
    float s = 0.f, d = 0.f;
    #pragma unroll
    for (int f = 0; f < NHID; ++f){
      float v = hs[r][hd * NHID + f];
      s = fmaf(v, aw[f], s);
      d = fmaf(v, aw[NHID + f], d);
    }
    src[hd * NN + row0 + r] = s;
    dst[hd * NN + row0 + r] = d;
  }
}

// K2: register-tiled rank-by-counting + scatter. 64 i-blocks x 4 heads, 512 thr.
// Thread owns 8 i-keys in VGPRs; each ds_read_b128 (2 keys) feeds 16 compares.
// keys2 rows padded to 66 u64 -> the wave's 8 distinct b128 addrs hit disjoint
// 4-bank spans (132 words/row, 132%32=4), 8-lane broadcast each: conflict-free.
__global__ __launch_bounds__(512) void ranksc_k(const float* __restrict__ dst,
                                                unsigned long long* __restrict__ ksort,
                                                unsigned* __restrict__ dkey){
  int ib = blockIdx.x;   // 0..63 -> 64 i's each
  int hd = blockIdx.y;   // 0..3
  __shared__ __align__(16) unsigned long long keys2[64][66];  // 33.8 KB
  __shared__ int wsum[8][64];                                 // 2 KB
  int t = threadIdx.x;
  const float* dp = dst + hd * NN;
  for (int j = t; j < NN; j += 512)
    keys2[j >> 6][j & 63] = ((unsigned long long)fkey(dp[j]) << 32) | (unsigned)j;
  __syncthreads();
  int g = t >> 3, c = t & 7;           // g: j-range (64 j's); c: i-set (8 i's)
  unsigned long long mk[8];
  #pragma unroll
  for (int r = 0; r < 8; ++r) mk[r] = keys2[ib][c * 8 + r];
  int cnt[8] = {0, 0, 0, 0, 0, 0, 0, 0};
  const ulonglong2* kp = (const ulonglong2*)&keys2[g][0];
  #pragma unroll 4
  for (int q = 0; q < 32; ++q){
    ulonglong2 kk = kp[q];
    #pragma unroll
    for (int r = 0; r < 8; ++r){
      cnt[r] += (kk.x < mk[r]) ? 1 : 0;
      cnt[r] += (kk.y < mk[r]) ? 1 : 0;
    }
  }
  // reduce over lanes with same c (distance 8,16,32 within the wave)
  #pragma unroll
  for (int r = 0; r < 8; ++r){
    cnt[r] += __shfl_down(cnt[r], 32);
    cnt[r] += __shfl_down(cnt[r], 16);
    cnt[r] += __shfl_down(cnt[r], 8);
  }
  int w = t >> 6;                      // wave id 0..7
  if ((t & 63) < 8){
    #pragma unroll
    for (int r = 0; r < 8; ++r) wsum[w][c * 8 + r] = cnt[r];
  }
  __syncthreads();
  if (t < 64){
    int rank = 0;
    #pragma unroll
    for (int w2 = 0; w2 < 8; ++w2) rank += wsum[w2][t];
    unsigned long long key = keys2[ib][t];
    ksort[hd * NN + rank] = key;       // unique rank (idx breaks ties)
    dkey[hd * NN + rank]  = (unsigned)(key >> 32);
  }
}

// K3: per-(head,chunk) local prefix/suffix scans -> transposed padded PL2/SL2.
__global__ __launch_bounds__(256) void scanA_k(const float* __restrict__ h,
                                               const unsigned long long* __restrict__ ksort,
                                               float* __restrict__ PL2,
                                               float* __restrict__ SL2,
                                               float* __restrict__ ctP,
                                               float* __restrict__ ctS){
  int ch = blockIdx.x;   // 64
  int hd = blockIdx.y;   // 4
  int t = threadIdx.x;
  int base = ch * CHUNK;
  __shared__ float e02[CHUNK], e1[CHUNK];
  __shared__ int   pms[CHUNK];
  __shared__ float hl[CHUNK][RPAD];
  __shared__ float PLs[CHUNK][RPAD], SLs[CHUNK][RPAD];
  if (t < CHUNK){
    unsigned long long key = ksort[hd * NN + base + t];
    float d = fkey_inv((unsigned)(key >> 32));
    e02[t] = __expf(0.2f * d);
    e1[t]  = __expf(d);
    pms[t] = (int)(unsigned)key;
    hl[t][16] = 1.0f;
  }
  __syncthreads();
  {
    int col = t & 15, r0 = t >> 4;
    #pragma unroll
    for (int it = 0; it < 4; ++it){
      int r = it * 16 + r0;
      hl[r][col] = h[pms[r] * NCOL + hd * NHID + col];
    }
  }
  __syncthreads();
  if (t < NCOLS){
    int col = t;
    float run = 0.f;
    #pragma unroll
    for (int r = 0; r < CHUNK; ++r){
      PLs[r][col] = run;                        // exclusive
      run = fmaf(e02[r], hl[r][col], run);
    }
    ctP[ch * 68 + hd * 17 + col] = run;
  } else if (t >= 64 && t < 64 + NCOLS){
    int col = t - 64;
    float rs = 0.f;
    #pragma unroll
    for (int r = CHUNK - 1; r >= 0; --r){
      rs = fmaf(e1[r], hl[r][col], rs);
      SLs[r][col] = rs;                         // inclusive
    }
    ctS[ch * 68 + hd * 17 + col] = rs;
  }
  __syncthreads();
  // contiguous coalesced writes (pad cols carry garbage, never read)
  #pragma unroll
  for (int n = 0; n < 5; ++n){
    int idx = n * 256 + t;                      // 5*256 = 64*20
    int r = idx / RPAD, c = idx % RPAD;
    PL2[(hd * NN + base + r) * RPAD + c] = PLs[r][c];
    SL2[(hd * NN + base + r) * RPAD + c] = SLs[r][c];
  }
}

// K4: LDS ct-scan + LDS binary search + float4 combine. 256 blocks x 64 pairs.
__global__ __launch_bounds__(256) void out_k(const float* __restrict__ src,
                                             const unsigned* __restrict__ dkey,
                                             const float* __restrict__ PL2,
                                             const float* __restrict__ SL2,
                                             const float* __restrict__ ctP,
                                             const float* __restrict__ ctS,
                                             float* __restrict__ out){
  __shared__ __align__(16) unsigned dk[NN];        // 16 KB sorted keys
  __shared__ __align__(16) float oP[NCH + 1][68];  // 17.7 KB (row NCH = totals)
  __shared__ __align__(16) float oS[NCH][68];      // 17.4 KB
  int t = threadIdx.x;
  int hd = blockIdx.x & 3, ig = blockIdx.x >> 2;
  const unsigned* dkp = dkey + hd * NN;
  #pragma unroll
  for (int n = 0; n < 4; ++n)
    ((uint4*)dk)[n * 256 + t] = ((const uint4*)dkp)[n * 256 + t];
  #pragma unroll
  for (int n = 0; n < 5; ++n){
    int idx = n * 256 + t;
    if (idx < 1088){
      ((float4*)&oP[0][0])[idx] = ((const float4*)ctP)[idx];
      ((float4*)&oS[0][0])[idx] = ((const float4*)ctS)[idx];
    }
  }
  __syncthreads();
  if (t < 68){
    float run = 0.f;
    #pragma unroll
    for (int c = 0; c < NCH; ++c){ float v = oP[c][t]; oP[c][t] = run; run += v; }
    oP[NCH][t] = run;
  } else if (t >= 128 && t < 196){
    int cc = t - 128;
    float rs = 0.f;
    #pragma unroll
    for (int c = NCH - 1; c >= 0; --c){ float v = oS[c][cc]; oS[c][cc] = rs; rs += v; }
  }
  __syncthreads();
  int p = t >> 2, q = t & 3;            // 64 pairs x 4 threads
  int i = ig * 64 + p;
  float s = src[hd * NN + i];
  unsigned tu = fkey(-s);
  int lo = 0, hi = NN;
  while (lo < hi){                      // 12 LDS-latency hops
    int mid = (lo + hi) >> 1;
    if (dk[mid] < tu) lo = mid + 1; else hi = mid;
  }
  int k = lo;                           // ranks < k take the 0.2 branch
  float4 res;
  if (k == NN){                         // all in 0.2 branch: alpha cancels
    float inv = 1.0f / oP[NCH][hd * 17 + 16];
    res.x = oP[NCH][hd * 17 + q * 4 + 0] * inv;
    res.y = oP[NCH][hd * 17 + q * 4 + 1] * inv;
    res.z = oP[NCH][hd * 17 + q * 4 + 2] * inv;
    res.w = oP[NCH][hd * 17 + q * 4 + 3] * inv;
  } else {
    float dmax = fkey_inv(dk[NN - 1]);
    float m = lrelu(s + dmax);
    float alpha = __expf(0.2f * s - m);
    float beta  = __expf(s - m);
    int ch = k >> 6;
    const float* P2 = PL2 + (size_t)(hd * NN + k) * RPAD;
    const float* S2 = SL2 + (size_t)(hd * NN + k) * RPAD;
    float4 p4 = *(const float4*)(P2 + q * 4);
    float4 s4 = *(const float4*)(S2 + q * 4);
    float den = alpha * (P2[16] + oP[ch][hd * 17 + 16])
              + beta  * (S2[16] + oS[ch][hd * 17 + 16]);
    float inv = 1.0f / den;
    res.x = (alpha * (p4.x + oP[ch][hd * 17 + q * 4 + 0])
           + beta  * (s4.x + oS[ch][hd * 17 + q * 4 + 0])) * inv;
    res.y = (alpha * (p4.y + oP[ch][hd * 17 + q * 4 + 1])
           + beta  * (s4.y + oS[ch][hd * 17 + q * 4 + 1])) * inv;
    res.z = (alpha * (p4.z + oP[ch][hd * 17 + q * 4 + 2])
           + beta  * (s4.z + oS[ch][hd * 17 + q * 4 + 2])) * inv;
    res.w = (alpha * (p4.w + oP[ch][hd * 17 + q * 4 + 3])
           + beta  * (s4.w + oS[ch][hd * 17 + q * 4 + 3])) * inv;
  }
  *(float4*)(out + i * NCOL + hd * NHID + q * 4) = res;
}

extern "C" void kernel_launch(void* const* d_in, const int* in_sizes, int n_in,
                              void* d_out, int out_size, void* d_ws, size_t ws_size,
                              hipStream_t stream){
  const float* x  = (const float*)d_in[0];
  // d_in[1] = adj : UNUSED by the reference (no masking) — never read it.
  const float* W  = (const float*)d_in[2];
  const float* aw = (const float*)d_in[3];
  float* out = (float*)d_out;
  float* ws  = (float*)d_ws;

  float*              h     = ws;                                   // 262144
  float*              src   = ws + 262144;                          // 16384
  float*              dst   = ws + 278528;                          // 16384
  unsigned long long* ksort = (unsigned long long*)(ws + 294912);   // 16384 u64 (16B-aligned)
  unsigned*           dkey  = (unsigned*)(ws + 327680);             // 16384
  float*              PL2   = ws + 344064;                          // 4*4096*20 = 327680
  float*              SL2   = ws + 671744;                          // 327680
  float*              ctP   = ws + 999424;                          // 4352
  float*              ctS   = ws + 1003776;                         // 4352
  // total ~4.03 MB

  gemm_h_k<<<512, 256, 0, stream>>>(x, W, aw, h, src, dst);
  ranksc_k<<<dim3(64, NHEAD), 512, 0, stream>>>(dst, ksort, dkey);
  scanA_k<<<dim3(NCH, NHEAD), 256, 0, stream>>>(h, ksort, PL2, SL2, ctP, ctS);
  out_k<<<256, 256, 0, stream>>>(src, dkey, PL2, SL2, ctP, ctS, out);
}